// Round 5
// baseline (207.850 us; speedup 1.0000x reference)
//
#include <hip/hip_runtime.h>
#include <hip/hip_bf16.h>
#include <math.h>

#define BB 64
#define TT 500
#define DD 64
#define SS 50
#define CH 20
#define NCH (TT / CH)   // 25

__device__ __forceinline__ float sigmoidf_(float x) { return 1.0f / (1.0f + __expf(-x)); }

// ---------------------------------------------------------------------------
// Kernel 1: tables. blocks [0,ncon): wTab[c][50] = softmax(embed_key[c]·Mk^T)
//           blocks [ncon, ncon+nv): eTab[x] = sigmoid(ev@We+be), aTab = tanh(...)
// ---------------------------------------------------------------------------
__global__ __launch_bounds__(64) void k1_tables(
    const float* __restrict__ embed_key,
    const float* __restrict__ embed_value,
    const float* __restrict__ Mk,
    const float* __restrict__ We, const float* __restrict__ be,
    const float* __restrict__ Wa, const float* __restrict__ ba,
    int ncon, int nv,
    float* __restrict__ wTab, float* __restrict__ eTab, float* __restrict__ aTab)
{
    const int lane = threadIdx.x;
    if ((int)blockIdx.x < ncon) {
        const int c = blockIdx.x;
        __shared__ float mkS[SS][DD + 1];
        __shared__ float kS[DD];
        kS[lane] = embed_key[c * DD + lane];
        for (int s = 0; s < SS; ++s)
            mkS[s][lane] = Mk[s * DD + lane];
        __syncthreads();

        float sc = -1e30f;
        if (lane < SS) {
            float acc = 0.f;
            #pragma unroll
            for (int dd = 0; dd < DD; ++dd)
                acc = fmaf(kS[dd], mkS[lane][dd], acc);
            sc = acc;
        }
        float m = sc;
        #pragma unroll
        for (int off = 32; off >= 1; off >>= 1)
            m = fmaxf(m, __shfl_xor(m, off));
        float ex = (lane < SS) ? __expf(sc - m) : 0.f;
        float ssum = ex;
        #pragma unroll
        for (int off = 32; off >= 1; off >>= 1)
            ssum += __shfl_xor(ssum, off);
        if (lane < SS)
            wTab[c * SS + lane] = ex / ssum;
    } else {
        const int x = blockIdx.x - ncon;
        __shared__ float vS[DD];
        vS[lane] = embed_value[x * DD + lane];
        __syncthreads();
        float acc_e = be[lane];
        float acc_a = ba[lane];
        #pragma unroll
        for (int i = 0; i < DD; ++i) {
            const float vi = vS[i];
            acc_e = fmaf(vi, We[i * DD + lane], acc_e);
            acc_a = fmaf(vi, Wa[i * DD + lane], acc_a);
        }
        eTab[x * DD + lane] = sigmoidf_(acc_e);
        aTab[x * DD + lane] = tanhf(acc_a);
    }
}

// ---------------------------------------------------------------------------
// Kernel 2: scan. grid = BB*4 blocks (b, sgB), 64 threads (lane = d).
// Block (b,sgB) owns 12-13 s-states in regs. All chunk operands live in
// NAMED REGISTERS (no LDS staging, no barriers in main loop, no atomics):
//   e/a: per-lane gathers, already lane-correct.
//   w:   16-wide slice loads, redistributed per-step via __shfl(const lane)
//        -> readlane/SGPR broadcast.
// Chunk-level A/B register ping-pong: next chunk's 45 loads issue ~2000cy
// before use. Partials plain-stored to per-sgB plane; k3 sums planes.
// ---------------------------------------------------------------------------
#define GW(WD, KK, T0) {                                                     \
    const int idx_ = lane + 64 * (KK);                                       \
    const int tt_ = idx_ >> 4, j_ = idx_ & 15;                               \
    const int s_ = st + j_;                                                  \
    WD = (s_ < en) ? wTab[cL[(T0) + tt_] * SS + s_] : 0.f; }

#define GLOAD(P, T0)                                                         \
    GW(w##P##0, 0, T0) GW(w##P##1, 1, T0) GW(w##P##2, 2, T0)                 \
    GW(w##P##3, 3, T0) GW(w##P##4, 4, T0)                                    \
    _Pragma("unroll")                                                        \
    for (int tt = 0; tt < CH; ++tt) {                                        \
        const int xx_ = xL[(T0) + tt];                                       \
        e##P[tt] = eTab[xx_ * DD + lane];                                    \
        a##P[tt] = aTab[xx_ * DD + lane]; }

#define U1(JJ, WREG) {                                                       \
    const float w_ = __shfl((WREG), q_ * 16 + (JJ));                         \
    const float mv_ = Mv[JJ];                                                \
    if ((JJ) & 1) r1 = fmaf(w_, mv_, r1); else r0 = fmaf(w_, mv_, r0);       \
    Mv[JJ] = fmaf(-w_, fmaf(e_, mv_, -a_), mv_); }

#define STEP(P, WREG, tc, T0) {                                              \
    const float e_ = e##P[tc], a_ = a##P[tc];                                \
    const int q_ = (tc) & 3;                                                 \
    float r0 = 0.f, r1 = 0.f;                                                \
    U1(0, WREG)  U1(1, WREG)  U1(2, WREG)  U1(3, WREG)                       \
    U1(4, WREG)  U1(5, WREG)  U1(6, WREG)  U1(7, WREG)                       \
    U1(8, WREG)  U1(9, WREG)  U1(10, WREG) U1(11, WREG) U1(12, WREG)         \
    rp[(size_t)((T0) + (tc)) * DD] = r0 + r1; }

#define CCOMP(P, T0)                                                         \
    STEP(P, w##P##0, 0, T0)  STEP(P, w##P##0, 1, T0)                         \
    STEP(P, w##P##0, 2, T0)  STEP(P, w##P##0, 3, T0)                         \
    STEP(P, w##P##1, 4, T0)  STEP(P, w##P##1, 5, T0)                         \
    STEP(P, w##P##1, 6, T0)  STEP(P, w##P##1, 7, T0)                         \
    STEP(P, w##P##2, 8, T0)  STEP(P, w##P##2, 9, T0)                         \
    STEP(P, w##P##2, 10, T0) STEP(P, w##P##2, 11, T0)                        \
    STEP(P, w##P##3, 12, T0) STEP(P, w##P##3, 13, T0)                        \
    STEP(P, w##P##3, 14, T0) STEP(P, w##P##3, 15, T0)                        \
    STEP(P, w##P##4, 16, T0) STEP(P, w##P##4, 17, T0)                        \
    STEP(P, w##P##4, 18, T0) STEP(P, w##P##4, 19, T0)

__global__ __launch_bounds__(64, 1) void k2_scan(
    const int* __restrict__ cseq,
    const int* __restrict__ corr,
    const int* __restrict__ ncp,
    const float* __restrict__ wTab,
    const float* __restrict__ eTab,
    const float* __restrict__ aTab,
    const float* __restrict__ Mv0,
    float* __restrict__ rPart)
{
    const int b = blockIdx.x >> 2;
    const int sgB = blockIdx.x & 3;
    const int lane = threadIdx.x;
    const int nc = ncp[0];

    __shared__ int xL[TT];
    __shared__ int cL[TT];
    for (int i = lane; i < TT; i += 64) {
        const int c = cseq[b * TT + i];
        cL[i] = c;
        xL[i] = c + nc * corr[b * TT + i];
    }
    __syncthreads();

    const int st = (SS * sgB) >> 2;          // {0,12,25,37}
    const int en = (SS * (sgB + 1)) >> 2;    // {12,25,37,50}

    float Mv[13];
    #pragma unroll
    for (int j = 0; j < 13; ++j) {
        const int s = st + j;
        Mv[j] = (s < en) ? Mv0[s * DD + lane] : 0.f;
    }

    float* rp = rPart + ((size_t)sgB * BB + b) * TT * DD + lane;

    float eA[CH], aA[CH], eB[CH], aB[CH];
    float wA0, wA1, wA2, wA3, wA4, wB0, wB1, wB2, wB3, wB4;

    GLOAD(A, 0)

    for (int ch = 0; ch < NCH - 1; ch += 2) {
        const int T0a = ch * CH;
        const int T0b = T0a + CH;
        const int T0c = T0a + 2 * CH;        // <= (NCH-1)*CH, always valid
        GLOAD(B, T0b)
        CCOMP(A, T0a)
        GLOAD(A, T0c)
        CCOMP(B, T0b)
    }
    CCOMP(A, (NCH - 1) * CH)                 // tail chunk 24
}

// ---------------------------------------------------------------------------
// Kernel 3: output head as a tiled [64bt x 64j] fp32 GEMM with Wf in LDS.
// 500 blocks x 256 threads; thread (ty,tx) computes a 4bt x 4j register tile.
// catT staging sums the 4 rPart planes.
// ---------------------------------------------------------------------------
__global__ __launch_bounds__(256) void k3_output(
    const int* __restrict__ cseq,
    const float* __restrict__ embed_key,
    const float* __restrict__ rPart,
    const float* __restrict__ Wf, const float* __restrict__ bf,
    const float* __restrict__ Wab, const float* __restrict__ bab,
    const float* __restrict__ Wd, const float* __restrict__ bd,
    float* __restrict__ out)
{
    const int tid = threadIdx.x;
    const int tx = tid & 15, ty = tid >> 4;
    const int bt0 = blockIdx.x * 64;

    __shared__ float __align__(16) wfS[128][64];
    __shared__ float __align__(16) catT[128][68];
    __shared__ float qS[64];
    __shared__ float redS[64][17];

    #pragma unroll
    for (int k = 0; k < 8; ++k) {
        const int idx = tid + k * 256;
        ((float4*)wfS)[idx] = ((const float4*)Wf)[idx];
    }

    {
        const int d = tid & 63;
        const int g = tid >> 6;
        const float wd = Wd[d];
        #pragma unroll
        for (int m = 0; m < 16; ++m) {
            const int btl = g + 4 * m;
            const int bt = bt0 + btl;
            const int c = cseq[bt];
            const size_t o = (size_t)bt * DD + d;
            const float r = rPart[o]
                          + rPart[(size_t)1 * BB * TT * DD + o]
                          + rPart[(size_t)2 * BB * TT * DD + o]
                          + rPart[(size_t)3 * BB * TT * DD + o];
            const float kv = embed_key[c * DD + d];
            catT[d][btl] = r;
            catT[64 + d][btl] = kv;
            float q = kv * wd;
            #pragma unroll
            for (int off = 32; off >= 1; off >>= 1)
                q += __shfl_xor(q, off);
            if (d == 0) qS[btl] = q;
        }
    }
    __syncthreads();

    float acc[4][4] = {{0.f}};
    #pragma unroll 8
    for (int i = 0; i < 128; ++i) {
        const float4 wf = *(const float4*)&wfS[i][tx * 4];
        const float4 ct = *(const float4*)&catT[i][ty * 4];
        acc[0][0] = fmaf(ct.x, wf.x, acc[0][0]);
        acc[0][1] = fmaf(ct.x, wf.y, acc[0][1]);
        acc[0][2] = fmaf(ct.x, wf.z, acc[0][2]);
        acc[0][3] = fmaf(ct.x, wf.w, acc[0][3]);
        acc[1][0] = fmaf(ct.y, wf.x, acc[1][0]);
        acc[1][1] = fmaf(ct.y, wf.y, acc[1][1]);
        acc[1][2] = fmaf(ct.y, wf.z, acc[1][2]);
        acc[1][3] = fmaf(ct.y, wf.w, acc[1][3]);
        acc[2][0] = fmaf(ct.z, wf.x, acc[2][0]);
        acc[2][1] = fmaf(ct.z, wf.y, acc[2][1]);
        acc[2][2] = fmaf(ct.z, wf.z, acc[2][2]);
        acc[2][3] = fmaf(ct.z, wf.w, acc[2][3]);
        acc[3][0] = fmaf(ct.w, wf.x, acc[3][0]);
        acc[3][1] = fmaf(ct.w, wf.y, acc[3][1]);
        acc[3][2] = fmaf(ct.w, wf.z, acc[3][2]);
        acc[3][3] = fmaf(ct.w, wf.w, acc[3][3]);
    }

    #pragma unroll
    for (int ii = 0; ii < 4; ++ii) {
        float p = 0.f;
        #pragma unroll
        for (int jj = 0; jj < 4; ++jj) {
            const int j = tx * 4 + jj;
            const float f = tanhf(acc[ii][jj] + bf[j]);
            p = fmaf(f, Wab[j], p);
        }
        redS[ty * 4 + ii][tx] = p;
    }
    __syncthreads();

    if (tid < 64) {
        const int btl = tid;
        float s = 0.f;
        #pragma unroll
        for (int t2 = 0; t2 < 16; ++t2)
            s += redS[btl][t2];
        const float stu  = tanhf(s + bab[0]);
        const float diff = tanhf(qS[btl] + bd[0]);
        out[bt0 + btl] = sigmoidf_(3.0f * stu - diff);
    }
}

// ---------------------------------------------------------------------------
extern "C" void kernel_launch(void* const* d_in, const int* in_sizes, int n_in,
                              void* d_out, int out_size, void* d_ws, size_t ws_size,
                              hipStream_t stream)
{
    const int*   concept_seq = (const int*)  d_in[0];
    const int*   correct_seq = (const int*)  d_in[1];
    const int*   num_concept = (const int*)  d_in[2];
    const float* embed_key   = (const float*)d_in[3];
    const float* embed_value = (const float*)d_in[4];
    const float* Mk          = (const float*)d_in[5];
    const float* Mv0         = (const float*)d_in[6];
    const float* Wf          = (const float*)d_in[7];
    const float* bf          = (const float*)d_in[8];
    const float* We          = (const float*)d_in[9];
    const float* be          = (const float*)d_in[10];
    const float* Wa          = (const float*)d_in[11];
    const float* ba          = (const float*)d_in[12];
    const float* Wab         = (const float*)d_in[13];
    const float* bab         = (const float*)d_in[14];
    const float* Wd          = (const float*)d_in[15];
    const float* bd          = (const float*)d_in[16];
    float* out = (float*)d_out;

    const int NCON = in_sizes[3] / DD;   // 1024
    const int NV   = in_sizes[4] / DD;   // 2048

    float* wTab  = (float*)d_ws;                       // NCON*SS
    float* eTab  = wTab + (size_t)NCON * SS;           // NV*DD
    float* aTab  = eTab + (size_t)NV * DD;             // NV*DD
    float* rPart = aTab + (size_t)NV * DD;             // 4 * BB*TT*DD

    k1_tables<<<NCON + NV, 64, 0, stream>>>(
        embed_key, embed_value, Mk, We, be, Wa, ba,
        NCON, NV, wTab, eTab, aTab);

    k2_scan<<<BB * 4, 64, 0, stream>>>(
        concept_seq, correct_seq, num_concept,
        wTab, eTab, aTab, Mv0, rPart);

    k3_output<<<(BB * TT) / 64, 256, 0, stream>>>(
        concept_seq, embed_key, rPart,
        Wf, bf, Wab, bab, Wd, bd, out);
}

// Round 6
// 179.919 us; speedup vs baseline: 1.1552x; 1.1552x over previous
//
#include <hip/hip_runtime.h>
#include <hip/hip_bf16.h>
#include <math.h>

#define BB 64
#define TT 500
#define DD 64
#define SS 50
#define CH 20
#define NCH (TT / CH)   // 25

__device__ __forceinline__ float sigmoidf_(float x) { return 1.0f / (1.0f + __expf(-x)); }

// v_readlane_b32: VALU->SGPR broadcast (~2cy). __shfl would emit
// ds_bpermute_b32 (LDS pipe, ~60cy) -- measured 630cy/step in round 5.
__device__ __forceinline__ float rdlane(float v, int l) {
    return __int_as_float(__builtin_amdgcn_readlane(__float_as_int(v), l));
}

// ---------------------------------------------------------------------------
// Kernel 1: tables. blocks [0,ncon): wTab[c][50] = softmax(embed_key[c]·Mk^T)
//           blocks [ncon, ncon+nv): eTab[x] = sigmoid(ev@We+be), aTab = tanh(...)
// ---------------------------------------------------------------------------
__global__ __launch_bounds__(64) void k1_tables(
    const float* __restrict__ embed_key,
    const float* __restrict__ embed_value,
    const float* __restrict__ Mk,
    const float* __restrict__ We, const float* __restrict__ be,
    const float* __restrict__ Wa, const float* __restrict__ ba,
    int ncon, int nv,
    float* __restrict__ wTab, float* __restrict__ eTab, float* __restrict__ aTab)
{
    const int lane = threadIdx.x;
    if ((int)blockIdx.x < ncon) {
        const int c = blockIdx.x;
        __shared__ float mkS[SS][DD + 1];
        __shared__ float kS[DD];
        kS[lane] = embed_key[c * DD + lane];
        for (int s = 0; s < SS; ++s)
            mkS[s][lane] = Mk[s * DD + lane];
        __syncthreads();

        float sc = -1e30f;
        if (lane < SS) {
            float acc = 0.f;
            #pragma unroll
            for (int dd = 0; dd < DD; ++dd)
                acc = fmaf(kS[dd], mkS[lane][dd], acc);
            sc = acc;
        }
        float m = sc;
        #pragma unroll
        for (int off = 32; off >= 1; off >>= 1)
            m = fmaxf(m, __shfl_xor(m, off));
        float ex = (lane < SS) ? __expf(sc - m) : 0.f;
        float ssum = ex;
        #pragma unroll
        for (int off = 32; off >= 1; off >>= 1)
            ssum += __shfl_xor(ssum, off);
        if (lane < SS)
            wTab[c * SS + lane] = ex / ssum;
    } else {
        const int x = blockIdx.x - ncon;
        __shared__ float vS[DD];
        vS[lane] = embed_value[x * DD + lane];
        __syncthreads();
        float acc_e = be[lane];
        float acc_a = ba[lane];
        #pragma unroll
        for (int i = 0; i < DD; ++i) {
            const float vi = vS[i];
            acc_e = fmaf(vi, We[i * DD + lane], acc_e);
            acc_a = fmaf(vi, Wa[i * DD + lane], acc_a);
        }
        eTab[x * DD + lane] = sigmoidf_(acc_e);
        aTab[x * DD + lane] = tanhf(acc_a);
    }
}

// ---------------------------------------------------------------------------
// Kernel 2: scan. grid = BB*4 blocks (b, sgB), 64 threads (lane = d).
// Block (b,sgB) owns 12-13 s-states in regs. All chunk operands in NAMED
// registers; w broadcast per step via v_readlane (SGPR), batched 13-wide.
// Chunk-level A/B register ping-pong hides HBM/L2 latency. No LDS staging,
// no barriers in main loop, no atomics; partials to per-sgB plane.
// ---------------------------------------------------------------------------
#define GW(WD, KK, T0) {                                                     \
    const int idx_ = lane + 64 * (KK);                                       \
    const int tt_ = idx_ >> 4, j_ = idx_ & 15;                               \
    const int s_ = st + j_;                                                  \
    WD = (s_ < en) ? wTab[cL[(T0) + tt_] * SS + s_] : 0.f; }

#define GLOAD(P, T0)                                                         \
    GW(w##P##0, 0, T0) GW(w##P##1, 1, T0) GW(w##P##2, 2, T0)                 \
    GW(w##P##3, 3, T0) GW(w##P##4, 4, T0)                                    \
    _Pragma("unroll")                                                        \
    for (int tt = 0; tt < CH; ++tt) {                                        \
        const int xx_ = xL[(T0) + tt];                                       \
        e##P[tt] = eTab[xx_ * DD + lane];                                    \
        a##P[tt] = aTab[xx_ * DD + lane]; }

#define UPD(WW, JJ) {                                                        \
    const float mv_ = Mv[JJ];                                                \
    if ((JJ) & 1) r1 = fmaf(WW, mv_, r1); else r0 = fmaf(WW, mv_, r0);       \
    Mv[JJ] = fmaf(-(WW), fmaf(e_, mv_, -a_), mv_); }

#define STEP(P, WREG, tc, T0) {                                              \
    const float e_ = e##P[tc], a_ = a##P[tc];                                \
    const int qb_ = ((tc) & 3) * 16;                                         \
    const float x0_  = rdlane(WREG, qb_ + 0);                                \
    const float x1_  = rdlane(WREG, qb_ + 1);                                \
    const float x2_  = rdlane(WREG, qb_ + 2);                                \
    const float x3_  = rdlane(WREG, qb_ + 3);                                \
    const float x4_  = rdlane(WREG, qb_ + 4);                                \
    const float x5_  = rdlane(WREG, qb_ + 5);                                \
    const float x6_  = rdlane(WREG, qb_ + 6);                                \
    const float x7_  = rdlane(WREG, qb_ + 7);                                \
    const float x8_  = rdlane(WREG, qb_ + 8);                                \
    const float x9_  = rdlane(WREG, qb_ + 9);                                \
    const float x10_ = rdlane(WREG, qb_ + 10);                               \
    const float x11_ = rdlane(WREG, qb_ + 11);                               \
    const float x12_ = rdlane(WREG, qb_ + 12);                               \
    float r0 = 0.f, r1 = 0.f;                                                \
    UPD(x0_, 0)  UPD(x1_, 1)  UPD(x2_, 2)  UPD(x3_, 3)                       \
    UPD(x4_, 4)  UPD(x5_, 5)  UPD(x6_, 6)  UPD(x7_, 7)                       \
    UPD(x8_, 8)  UPD(x9_, 9)  UPD(x10_, 10) UPD(x11_, 11) UPD(x12_, 12)      \
    rp[(size_t)((T0) + (tc)) * DD] = r0 + r1; }

#define CCOMP(P, T0)                                                         \
    STEP(P, w##P##0, 0, T0)  STEP(P, w##P##0, 1, T0)                         \
    STEP(P, w##P##0, 2, T0)  STEP(P, w##P##0, 3, T0)                         \
    STEP(P, w##P##1, 4, T0)  STEP(P, w##P##1, 5, T0)                         \
    STEP(P, w##P##1, 6, T0)  STEP(P, w##P##1, 7, T0)                         \
    STEP(P, w##P##2, 8, T0)  STEP(P, w##P##2, 9, T0)                         \
    STEP(P, w##P##2, 10, T0) STEP(P, w##P##2, 11, T0)                        \
    STEP(P, w##P##3, 12, T0) STEP(P, w##P##3, 13, T0)                        \
    STEP(P, w##P##3, 14, T0) STEP(P, w##P##3, 15, T0)                        \
    STEP(P, w##P##4, 16, T0) STEP(P, w##P##4, 17, T0)                        \
    STEP(P, w##P##4, 18, T0) STEP(P, w##P##4, 19, T0)

__global__ __launch_bounds__(64, 1) void k2_scan(
    const int* __restrict__ cseq,
    const int* __restrict__ corr,
    const int* __restrict__ ncp,
    const float* __restrict__ wTab,
    const float* __restrict__ eTab,
    const float* __restrict__ aTab,
    const float* __restrict__ Mv0,
    float* __restrict__ rPart)
{
    const int b = blockIdx.x >> 2;
    const int sgB = blockIdx.x & 3;
    const int lane = threadIdx.x;
    const int nc = ncp[0];

    __shared__ int xL[TT];
    __shared__ int cL[TT];
    for (int i = lane; i < TT; i += 64) {
        const int c = cseq[b * TT + i];
        cL[i] = c;
        xL[i] = c + nc * corr[b * TT + i];
    }
    __syncthreads();

    const int st = (SS * sgB) >> 2;          // {0,12,25,37}
    const int en = (SS * (sgB + 1)) >> 2;    // {12,25,37,50}

    float Mv[13];
    #pragma unroll
    for (int j = 0; j < 13; ++j) {
        const int s = st + j;
        Mv[j] = (s < en) ? Mv0[s * DD + lane] : 0.f;
    }

    float* rp = rPart + ((size_t)sgB * BB + b) * TT * DD + lane;

    float eA[CH], aA[CH], eB[CH], aB[CH];
    float wA0, wA1, wA2, wA3, wA4, wB0, wB1, wB2, wB3, wB4;

    GLOAD(A, 0)

    for (int ch = 0; ch < NCH - 1; ch += 2) {
        const int T0a = ch * CH;
        const int T0b = T0a + CH;
        const int T0c = T0a + 2 * CH;        // <= (NCH-1)*CH, always valid
        GLOAD(B, T0b)
        CCOMP(A, T0a)
        GLOAD(A, T0c)
        CCOMP(B, T0b)
    }
    CCOMP(A, (NCH - 1) * CH)                 // tail chunk 24
}

// ---------------------------------------------------------------------------
// Kernel 3: output head as a tiled [64bt x 64j] fp32 GEMM with Wf in LDS.
// 500 blocks x 256 threads; thread (ty,tx) computes a 4bt x 4j register tile.
// catT staging sums the 4 rPart planes.
// ---------------------------------------------------------------------------
__global__ __launch_bounds__(256) void k3_output(
    const int* __restrict__ cseq,
    const float* __restrict__ embed_key,
    const float* __restrict__ rPart,
    const float* __restrict__ Wf, const float* __restrict__ bf,
    const float* __restrict__ Wab, const float* __restrict__ bab,
    const float* __restrict__ Wd, const float* __restrict__ bd,
    float* __restrict__ out)
{
    const int tid = threadIdx.x;
    const int tx = tid & 15, ty = tid >> 4;
    const int bt0 = blockIdx.x * 64;

    __shared__ float __align__(16) wfS[128][64];
    __shared__ float __align__(16) catT[128][68];
    __shared__ float qS[64];
    __shared__ float redS[64][17];

    #pragma unroll
    for (int k = 0; k < 8; ++k) {
        const int idx = tid + k * 256;
        ((float4*)wfS)[idx] = ((const float4*)Wf)[idx];
    }

    {
        const int d = tid & 63;
        const int g = tid >> 6;
        const float wd = Wd[d];
        #pragma unroll
        for (int m = 0; m < 16; ++m) {
            const int btl = g + 4 * m;
            const int bt = bt0 + btl;
            const int c = cseq[bt];
            const size_t o = (size_t)bt * DD + d;
            const float r = rPart[o]
                          + rPart[(size_t)1 * BB * TT * DD + o]
                          + rPart[(size_t)2 * BB * TT * DD + o]
                          + rPart[(size_t)3 * BB * TT * DD + o];
            const float kv = embed_key[c * DD + d];
            catT[d][btl] = r;
            catT[64 + d][btl] = kv;
            float q = kv * wd;
            #pragma unroll
            for (int off = 32; off >= 1; off >>= 1)
                q += __shfl_xor(q, off);
            if (d == 0) qS[btl] = q;
        }
    }
    __syncthreads();

    float acc[4][4] = {{0.f}};
    #pragma unroll 8
    for (int i = 0; i < 128; ++i) {
        const float4 wf = *(const float4*)&wfS[i][tx * 4];
        const float4 ct = *(const float4*)&catT[i][ty * 4];
        acc[0][0] = fmaf(ct.x, wf.x, acc[0][0]);
        acc[0][1] = fmaf(ct.x, wf.y, acc[0][1]);
        acc[0][2] = fmaf(ct.x, wf.z, acc[0][2]);
        acc[0][3] = fmaf(ct.x, wf.w, acc[0][3]);
        acc[1][0] = fmaf(ct.y, wf.x, acc[1][0]);
        acc[1][1] = fmaf(ct.y, wf.y, acc[1][1]);
        acc[1][2] = fmaf(ct.y, wf.z, acc[1][2]);
        acc[1][3] = fmaf(ct.y, wf.w, acc[1][3]);
        acc[2][0] = fmaf(ct.z, wf.x, acc[2][0]);
        acc[2][1] = fmaf(ct.z, wf.y, acc[2][1]);
        acc[2][2] = fmaf(ct.z, wf.z, acc[2][2]);
        acc[2][3] = fmaf(ct.z, wf.w, acc[2][3]);
        acc[3][0] = fmaf(ct.w, wf.x, acc[3][0]);
        acc[3][1] = fmaf(ct.w, wf.y, acc[3][1]);
        acc[3][2] = fmaf(ct.w, wf.z, acc[3][2]);
        acc[3][3] = fmaf(ct.w, wf.w, acc[3][3]);
    }

    #pragma unroll
    for (int ii = 0; ii < 4; ++ii) {
        float p = 0.f;
        #pragma unroll
        for (int jj = 0; jj < 4; ++jj) {
            const int j = tx * 4 + jj;
            const float f = tanhf(acc[ii][jj] + bf[j]);
            p = fmaf(f, Wab[j], p);
        }
        redS[ty * 4 + ii][tx] = p;
    }
    __syncthreads();

    if (tid < 64) {
        const int btl = tid;
        float s = 0.f;
        #pragma unroll
        for (int t2 = 0; t2 < 16; ++t2)
            s += redS[btl][t2];
        const float stu  = tanhf(s + bab[0]);
        const float diff = tanhf(qS[btl] + bd[0]);
        out[bt0 + btl] = sigmoidf_(3.0f * stu - diff);
    }
}

// ---------------------------------------------------------------------------
extern "C" void kernel_launch(void* const* d_in, const int* in_sizes, int n_in,
                              void* d_out, int out_size, void* d_ws, size_t ws_size,
                              hipStream_t stream)
{
    const int*   concept_seq = (const int*)  d_in[0];
    const int*   correct_seq = (const int*)  d_in[1];
    const int*   num_concept = (const int*)  d_in[2];
    const float* embed_key   = (const float*)d_in[3];
    const float* embed_value = (const float*)d_in[4];
    const float* Mk          = (const float*)d_in[5];
    const float* Mv0         = (const float*)d_in[6];
    const float* Wf          = (const float*)d_in[7];
    const float* bf          = (const float*)d_in[8];
    const float* We          = (const float*)d_in[9];
    const float* be          = (const float*)d_in[10];
    const float* Wa          = (const float*)d_in[11];
    const float* ba          = (const float*)d_in[12];
    const float* Wab         = (const float*)d_in[13];
    const float* bab         = (const float*)d_in[14];
    const float* Wd          = (const float*)d_in[15];
    const float* bd          = (const float*)d_in[16];
    float* out = (float*)d_out;

    const int NCON = in_sizes[3] / DD;   // 1024
    const int NV   = in_sizes[4] / DD;   // 2048

    float* wTab  = (float*)d_ws;                       // NCON*SS
    float* eTab  = wTab + (size_t)NCON * SS;           // NV*DD
    float* aTab  = eTab + (size_t)NV * DD;             // NV*DD
    float* rPart = aTab + (size_t)NV * DD;             // 4 * BB*TT*DD

    k1_tables<<<NCON + NV, 64, 0, stream>>>(
        embed_key, embed_value, Mk, We, be, Wa, ba,
        NCON, NV, wTab, eTab, aTab);

    k2_scan<<<BB * 4, 64, 0, stream>>>(
        concept_seq, correct_seq, num_concept,
        wTab, eTab, aTab, Mv0, rPart);

    k3_output<<<(BB * TT) / 64, 256, 0, stream>>>(
        concept_seq, embed_key, rPart,
        Wf, bf, Wab, bab, Wd, bd, out);
}

// Round 7
// 176.834 us; speedup vs baseline: 1.1754x; 1.0174x over previous
//
#include <hip/hip_runtime.h>
#include <hip/hip_bf16.h>
#include <math.h>

#define BB 64
#define TT 500
#define DD 64
#define SS 50
#define CH 20
#define NCH (TT / CH)   // 25

__device__ __forceinline__ float sigmoidf_(float x) { return 1.0f / (1.0f + __expf(-x)); }

// v_readlane_b32: VALU->SGPR broadcast (~2cy). __shfl would emit
// ds_bpermute_b32 (LDS pipe) -- measured 630cy/step in round 5.
__device__ __forceinline__ float rdlane(float v, int l) {
    return __int_as_float(__builtin_amdgcn_readlane(__float_as_int(v), l));
}

// Memory-clobber scheduling fence: loads issued above cannot sink below
// (round 6: compiler sank the chunk prefetch to just-before-use; VGPR=64
// proved operands weren't register-resident -> 266cy/step).
#define PIN() asm volatile("" ::: "memory")

// ---------------------------------------------------------------------------
// Kernel 1: tables. blocks [0,ncon): wTab[c][50] = softmax(embed_key[c]·Mk^T)
//   blocks [ncon,ncon+nv): eaTab[x][d] = {sigmoid(ev@We+be), tanh(ev@Wa+ba)}
// ---------------------------------------------------------------------------
__global__ __launch_bounds__(64) void k1_tables(
    const float* __restrict__ embed_key,
    const float* __restrict__ embed_value,
    const float* __restrict__ Mk,
    const float* __restrict__ We, const float* __restrict__ be,
    const float* __restrict__ Wa, const float* __restrict__ ba,
    int ncon, int nv,
    float* __restrict__ wTab, float* __restrict__ eaTab)
{
    const int lane = threadIdx.x;
    if ((int)blockIdx.x < ncon) {
        const int c = blockIdx.x;
        __shared__ float mkS[SS][DD + 1];
        __shared__ float kS[DD];
        kS[lane] = embed_key[c * DD + lane];
        for (int s = 0; s < SS; ++s)
            mkS[s][lane] = Mk[s * DD + lane];
        __syncthreads();

        float sc = -1e30f;
        if (lane < SS) {
            float acc = 0.f;
            #pragma unroll
            for (int dd = 0; dd < DD; ++dd)
                acc = fmaf(kS[dd], mkS[lane][dd], acc);
            sc = acc;
        }
        float m = sc;
        #pragma unroll
        for (int off = 32; off >= 1; off >>= 1)
            m = fmaxf(m, __shfl_xor(m, off));
        float ex = (lane < SS) ? __expf(sc - m) : 0.f;
        float ssum = ex;
        #pragma unroll
        for (int off = 32; off >= 1; off >>= 1)
            ssum += __shfl_xor(ssum, off);
        if (lane < SS)
            wTab[c * SS + lane] = ex / ssum;
    } else {
        const int x = blockIdx.x - ncon;
        __shared__ float vS[DD];
        vS[lane] = embed_value[x * DD + lane];
        __syncthreads();
        float acc_e = be[lane];
        float acc_a = ba[lane];
        #pragma unroll
        for (int i = 0; i < DD; ++i) {
            const float vi = vS[i];
            acc_e = fmaf(vi, We[i * DD + lane], acc_e);
            acc_a = fmaf(vi, Wa[i * DD + lane], acc_a);
        }
        float2 ea;
        ea.x = sigmoidf_(acc_e);
        ea.y = tanhf(acc_a);
        *(float2*)&eaTab[((size_t)x * DD + lane) * 2] = ea;
    }
}

// ---------------------------------------------------------------------------
// Kernel 2: scan. grid = BB*4 blocks (b, sgB), 64 threads (lane = d).
// Block (b,sgB) owns 12-13 s-states in regs. All chunk operands in NAMED
// registers; w broadcast per step via v_readlane. Chunk-level A/B register
// ping-pong with PIN() fences so the 25 loads/chunk actually issue one full
// chunk (~2300cy) ahead of use. No barriers in main loop, no atomics.
// ---------------------------------------------------------------------------
#define GW(WD, KK, T0) {                                                     \
    const int idx_ = lane + 64 * (KK);                                       \
    const int tt_ = idx_ >> 4, j_ = idx_ & 15;                               \
    const int s_ = st + j_;                                                  \
    WD = (s_ < en) ? wTab[cL[(T0) + tt_] * SS + s_] : 0.f; }

#define GLOAD(P, T0)                                                         \
    GW(w##P##0, 0, T0) GW(w##P##1, 1, T0) GW(w##P##2, 2, T0)                 \
    GW(w##P##3, 3, T0) GW(w##P##4, 4, T0)                                    \
    _Pragma("unroll")                                                        \
    for (int tt = 0; tt < CH; ++tt) {                                        \
        const int xx_ = xL[(T0) + tt];                                       \
        ea##P[tt] = *(const float2*)&eaTab[((size_t)xx_ * DD + lane) * 2]; }

#define UPD(WW, JJ) {                                                        \
    const float mv_ = Mv[JJ];                                                \
    if ((JJ) & 1) r1 = fmaf(WW, mv_, r1); else r0 = fmaf(WW, mv_, r0);       \
    Mv[JJ] = fmaf(-(WW), fmaf(e_, mv_, -a_), mv_); }

#define STEP(P, WREG, tc, T0) {                                              \
    const float e_ = ea##P[tc].x, a_ = ea##P[tc].y;                          \
    const int qb_ = ((tc) & 3) * 16;                                         \
    const float x0_  = rdlane(WREG, qb_ + 0);                                \
    const float x1_  = rdlane(WREG, qb_ + 1);                                \
    const float x2_  = rdlane(WREG, qb_ + 2);                                \
    const float x3_  = rdlane(WREG, qb_ + 3);                                \
    const float x4_  = rdlane(WREG, qb_ + 4);                                \
    const float x5_  = rdlane(WREG, qb_ + 5);                                \
    const float x6_  = rdlane(WREG, qb_ + 6);                                \
    const float x7_  = rdlane(WREG, qb_ + 7);                                \
    const float x8_  = rdlane(WREG, qb_ + 8);                                \
    const float x9_  = rdlane(WREG, qb_ + 9);                                \
    const float x10_ = rdlane(WREG, qb_ + 10);                               \
    const float x11_ = rdlane(WREG, qb_ + 11);                               \
    const float x12_ = rdlane(WREG, qb_ + 12);                               \
    float r0 = 0.f, r1 = 0.f;                                                \
    UPD(x0_, 0)  UPD(x1_, 1)  UPD(x2_, 2)  UPD(x3_, 3)                       \
    UPD(x4_, 4)  UPD(x5_, 5)  UPD(x6_, 6)  UPD(x7_, 7)                       \
    UPD(x8_, 8)  UPD(x9_, 9)  UPD(x10_, 10) UPD(x11_, 11) UPD(x12_, 12)      \
    rp[(size_t)((T0) + (tc)) * DD] = r0 + r1; }

#define CCOMP(P, T0)                                                         \
    STEP(P, w##P##0, 0, T0)  STEP(P, w##P##0, 1, T0)                         \
    STEP(P, w##P##0, 2, T0)  STEP(P, w##P##0, 3, T0)                         \
    STEP(P, w##P##1, 4, T0)  STEP(P, w##P##1, 5, T0)                         \
    STEP(P, w##P##1, 6, T0)  STEP(P, w##P##1, 7, T0)                         \
    STEP(P, w##P##2, 8, T0)  STEP(P, w##P##2, 9, T0)                         \
    STEP(P, w##P##2, 10, T0) STEP(P, w##P##2, 11, T0)                        \
    STEP(P, w##P##3, 12, T0) STEP(P, w##P##3, 13, T0)                        \
    STEP(P, w##P##3, 14, T0) STEP(P, w##P##3, 15, T0)                        \
    STEP(P, w##P##4, 16, T0) STEP(P, w##P##4, 17, T0)                        \
    STEP(P, w##P##4, 18, T0) STEP(P, w##P##4, 19, T0)

__global__ __launch_bounds__(64, 1) void k2_scan(
    const int* __restrict__ cseq,
    const int* __restrict__ corr,
    const int* __restrict__ ncp,
    const float* __restrict__ wTab,
    const float* __restrict__ eaTab,
    const float* __restrict__ Mv0,
    float* __restrict__ rPart)
{
    const int b = blockIdx.x >> 2;
    const int sgB = blockIdx.x & 3;
    const int lane = threadIdx.x;
    const int nc = ncp[0];

    __shared__ int xL[TT];
    __shared__ int cL[TT];
    for (int i = lane; i < TT; i += 64) {
        const int c = cseq[b * TT + i];
        cL[i] = c;
        xL[i] = c + nc * corr[b * TT + i];
    }
    __syncthreads();

    const int st = (SS * sgB) >> 2;          // {0,12,25,37}
    const int en = (SS * (sgB + 1)) >> 2;    // {12,25,37,50}

    float Mv[13];
    #pragma unroll
    for (int j = 0; j < 13; ++j) {
        const int s = st + j;
        Mv[j] = (s < en) ? Mv0[s * DD + lane] : 0.f;
    }

    float* rp = rPart + ((size_t)sgB * BB + b) * TT * DD + lane;

    float2 eaA[CH], eaB[CH];
    float wA0, wA1, wA2, wA3, wA4, wB0, wB1, wB2, wB3, wB4;

    GLOAD(A, 0)
    PIN();

    for (int ch = 0; ch < NCH - 1; ch += 2) {
        const int T0a = ch * CH;
        const int T0b = T0a + CH;
        const int T0c = T0a + 2 * CH;        // <= (NCH-1)*CH, always valid
        GLOAD(B, T0b)
        PIN();
        CCOMP(A, T0a)
        GLOAD(A, T0c)
        PIN();
        CCOMP(B, T0b)
    }
    CCOMP(A, (NCH - 1) * CH)                 // tail chunk 24
}

// ---------------------------------------------------------------------------
// Kernel 3: output head as a tiled [64bt x 64j] fp32 GEMM with Wf in LDS.
// 500 blocks x 256 threads; thread (ty,tx) computes a 4bt x 4j register tile.
// catT staging sums the 4 rPart planes.
// ---------------------------------------------------------------------------
__global__ __launch_bounds__(256) void k3_output(
    const int* __restrict__ cseq,
    const float* __restrict__ embed_key,
    const float* __restrict__ rPart,
    const float* __restrict__ Wf, const float* __restrict__ bf,
    const float* __restrict__ Wab, const float* __restrict__ bab,
    const float* __restrict__ Wd, const float* __restrict__ bd,
    float* __restrict__ out)
{
    const int tid = threadIdx.x;
    const int tx = tid & 15, ty = tid >> 4;
    const int bt0 = blockIdx.x * 64;

    __shared__ float __align__(16) wfS[128][64];
    __shared__ float __align__(16) catT[128][68];
    __shared__ float qS[64];
    __shared__ float redS[64][17];

    #pragma unroll
    for (int k = 0; k < 8; ++k) {
        const int idx = tid + k * 256;
        ((float4*)wfS)[idx] = ((const float4*)Wf)[idx];
    }

    {
        const int d = tid & 63;
        const int g = tid >> 6;
        const float wd = Wd[d];
        #pragma unroll
        for (int m = 0; m < 16; ++m) {
            const int btl = g + 4 * m;
            const int bt = bt0 + btl;
            const int c = cseq[bt];
            const size_t o = (size_t)bt * DD + d;
            const float r = rPart[o]
                          + rPart[(size_t)1 * BB * TT * DD + o]
                          + rPart[(size_t)2 * BB * TT * DD + o]
                          + rPart[(size_t)3 * BB * TT * DD + o];
            const float kv = embed_key[c * DD + d];
            catT[d][btl] = r;
            catT[64 + d][btl] = kv;
            float q = kv * wd;
            #pragma unroll
            for (int off = 32; off >= 1; off >>= 1)
                q += __shfl_xor(q, off);
            if (d == 0) qS[btl] = q;
        }
    }
    __syncthreads();

    float acc[4][4] = {{0.f}};
    #pragma unroll 8
    for (int i = 0; i < 128; ++i) {
        const float4 wf = *(const float4*)&wfS[i][tx * 4];
        const float4 ct = *(const float4*)&catT[i][ty * 4];
        acc[0][0] = fmaf(ct.x, wf.x, acc[0][0]);
        acc[0][1] = fmaf(ct.x, wf.y, acc[0][1]);
        acc[0][2] = fmaf(ct.x, wf.z, acc[0][2]);
        acc[0][3] = fmaf(ct.x, wf.w, acc[0][3]);
        acc[1][0] = fmaf(ct.y, wf.x, acc[1][0]);
        acc[1][1] = fmaf(ct.y, wf.y, acc[1][1]);
        acc[1][2] = fmaf(ct.y, wf.z, acc[1][2]);
        acc[1][3] = fmaf(ct.y, wf.w, acc[1][3]);
        acc[2][0] = fmaf(ct.z, wf.x, acc[2][0]);
        acc[2][1] = fmaf(ct.z, wf.y, acc[2][1]);
        acc[2][2] = fmaf(ct.z, wf.z, acc[2][2]);
        acc[2][3] = fmaf(ct.z, wf.w, acc[2][3]);
        acc[3][0] = fmaf(ct.w, wf.x, acc[3][0]);
        acc[3][1] = fmaf(ct.w, wf.y, acc[3][1]);
        acc[3][2] = fmaf(ct.w, wf.z, acc[3][2]);
        acc[3][3] = fmaf(ct.w, wf.w, acc[3][3]);
    }

    #pragma unroll
    for (int ii = 0; ii < 4; ++ii) {
        float p = 0.f;
        #pragma unroll
        for (int jj = 0; jj < 4; ++jj) {
            const int j = tx * 4 + jj;
            const float f = tanhf(acc[ii][jj] + bf[j]);
            p = fmaf(f, Wab[j], p);
        }
        redS[ty * 4 + ii][tx] = p;
    }
    __syncthreads();

    if (tid < 64) {
        const int btl = tid;
        float s = 0.f;
        #pragma unroll
        for (int t2 = 0; t2 < 16; ++t2)
            s += redS[btl][t2];
        const float stu  = tanhf(s + bab[0]);
        const float diff = tanhf(qS[btl] + bd[0]);
        out[bt0 + btl] = sigmoidf_(3.0f * stu - diff);
    }
}

// ---------------------------------------------------------------------------
extern "C" void kernel_launch(void* const* d_in, const int* in_sizes, int n_in,
                              void* d_out, int out_size, void* d_ws, size_t ws_size,
                              hipStream_t stream)
{
    const int*   concept_seq = (const int*)  d_in[0];
    const int*   correct_seq = (const int*)  d_in[1];
    const int*   num_concept = (const int*)  d_in[2];
    const float* embed_key   = (const float*)d_in[3];
    const float* embed_value = (const float*)d_in[4];
    const float* Mk          = (const float*)d_in[5];
    const float* Mv0         = (const float*)d_in[6];
    const float* Wf          = (const float*)d_in[7];
    const float* bf          = (const float*)d_in[8];
    const float* We          = (const float*)d_in[9];
    const float* be          = (const float*)d_in[10];
    const float* Wa          = (const float*)d_in[11];
    const float* ba          = (const float*)d_in[12];
    const float* Wab         = (const float*)d_in[13];
    const float* bab         = (const float*)d_in[14];
    const float* Wd          = (const float*)d_in[15];
    const float* bd          = (const float*)d_in[16];
    float* out = (float*)d_out;

    const int NCON = in_sizes[3] / DD;   // 1024
    const int NV   = in_sizes[4] / DD;   // 2048

    float* wTab  = (float*)d_ws;                       // NCON*SS
    float* eaTab = wTab + (size_t)NCON * SS;           // NV*DD*2
    float* rPart = eaTab + (size_t)NV * DD * 2;        // 4 * BB*TT*DD

    k1_tables<<<NCON + NV, 64, 0, stream>>>(
        embed_key, embed_value, Mk, We, be, Wa, ba,
        NCON, NV, wTab, eaTab);

    k2_scan<<<BB * 4, 64, 0, stream>>>(
        concept_seq, correct_seq, num_concept,
        wTab, eaTab, Mv0, rPart);

    k3_output<<<(BB * TT) / 64, 256, 0, stream>>>(
        concept_seq, embed_key, rPart,
        Wf, bf, Wab, bab, Wd, bd, out);
}